// Round 1
// baseline (194.082 us; speedup 1.0000x reference)
//
#include <hip/hip_runtime.h>

// DynamicSlidingWindowAttention — flash-attention w/ bf16 MFMA on gfx950.
// B=2 H=16 T=2048 D=64; windows per head: 256/512/1024/full (causal).
// Layouts per cdna_hip_programming.md §3 (m89/m91/m120-verified):
//   mfma_f32_16x16x32_bf16:  A[m=lane&15][k=quad*8+j], B[k=quad*8+j][n=lane&15],
//                            C/D: col=lane&15, row=quad*4+reg.

constexpr int Bc = 2, Hc = 16, Tc = 2048, Dc = 64;
constexpr int BQ = 64;   // q rows per block (16 per wave)
constexpr int BK = 64;   // keys per kv tile
constexpr int KSTR = 72; // K LDS row stride (bf16) — +8 pad: 2-way banks (free)
constexpr int VSTR = 72; // V^T LDS row stride
constexpr int PSTR = 72; // P LDS row stride
constexpr float SCALE = 0.125f;            // 1/sqrt(64)
constexpr float LOG2E = 1.44269504088896340736f;

typedef __attribute__((ext_vector_type(8))) short short8;
typedef __attribute__((ext_vector_type(4))) float float4v;

__device__ inline unsigned short f2bf(float f) {
    union { float f; unsigned u; } v; v.f = f;
    unsigned r = v.u + 0x7fffu + ((v.u >> 16) & 1u);   // RNE
    return (unsigned short)(r >> 16);
}

__device__ inline short8 pack8(const float* t) {
    short8 r;
#pragma unroll
    for (int j = 0; j < 8; j++) r[j] = (short)f2bf(t[j]);
    return r;
}

__global__ __launch_bounds__(256)
void dswa_kernel(const float* __restrict__ Q, const float* __restrict__ K,
                 const float* __restrict__ V, const int* __restrict__ wsz,
                 float* __restrict__ O) {
    __shared__ __align__(16) unsigned short Kl[BK * KSTR];      // [key][d]
    __shared__ __align__(16) unsigned short Vt[Dc * VSTR];      // [d][key]
    __shared__ __align__(16) unsigned short Pl[4 * 16 * PSTR];  // per-wave [row][key]

    const int blk = blockIdx.x;
    const int qt = blk & 31;            // T/BQ = 32 q-tiles
    const int h  = (blk >> 5) & 15;
    const int b  = blk >> 9;
    const int q0 = qt * BQ;
    const int win = wsz[h];

    const int tid  = threadIdx.x;
    const int wave = tid >> 6;
    const int lane = tid & 63;
    const int quad = lane >> 4;
    const int l16  = lane & 15;

    const size_t headoff = (size_t)(b * Hc + h) * Tc * Dc;
    const float* Qp = Q + headoff;
    const float* Kp = K + headoff;
    const float* Vp = V + headoff;
    float*       Op = O + headoff;

    // ---- Q fragments (held for whole kernel): rows q0+wave*16+l16, k=d ----
    short8 qf[2];
    {
        const int qrow = q0 + wave * 16 + l16;
#pragma unroll
        for (int c = 0; c < 2; c++) {
            const float* src = Qp + (size_t)qrow * Dc + c * 32 + quad * 8;
            float4v a = *(const float4v*)src;
            float4v d4 = *(const float4v*)(src + 4);
            float t[8] = {a[0], a[1], a[2], a[3], d4[0], d4[1], d4[2], d4[3]};
            qf[c] = pack8(t);
        }
    }

    float m_i[4], l_i[4];
    float4v acc[4];
#pragma unroll
    for (int r = 0; r < 4; r++) { m_i[r] = -1e30f; l_i[r] = 0.0f; }
#pragma unroll
    for (int nb = 0; nb < 4; nb++) acc[nb] = (float4v){0.f, 0.f, 0.f, 0.f};

    const int kv_lo = (max(0, q0 - win)) & ~(BK - 1);
    const int kv_hi = q0 + BQ;   // exclusive

    for (int kv0 = kv_lo; kv0 < kv_hi; kv0 += BK) {
        __syncthreads();   // previous tile's LDS reads done

        // ---- stage K tile [key][d] as bf16 (coalesced float4 reads) ----
#pragma unroll
        for (int i = 0; i < 2; i++) {
            const int key = (tid >> 3) + 32 * i;
            const int ds = (tid & 7) * 8;
            const float* src = Kp + (size_t)(kv0 + key) * Dc + ds;
            float4v a = *(const float4v*)src;
            float4v d4 = *(const float4v*)(src + 4);
            float t[8] = {a[0], a[1], a[2], a[3], d4[0], d4[1], d4[2], d4[3]};
            *(short8*)&Kl[key * KSTR + ds] = pack8(t);
        }
        // ---- stage V^T tile [d][key]: coalesced row reads, b128 LDS writes ----
#pragma unroll
        for (int i = 0; i < 2; i++) {
            const int d = tid & 63;
            const int kb = (tid >> 6) * 8 + 32 * i;
            float t[8];
#pragma unroll
            for (int j = 0; j < 8; j++) t[j] = Vp[(size_t)(kv0 + kb + j) * Dc + d];
            *(short8*)&Vt[d * VSTR + kb] = pack8(t);
        }
        __syncthreads();

        // ---- S = Q K^T : 4 n-blocks of 16 keys, 2 k-chunks over D ----
        float4v sB[4];
#pragma unroll
        for (int nb = 0; nb < 4; nb++) {
            float4v c = {0.f, 0.f, 0.f, 0.f};
#pragma unroll
            for (int ch = 0; ch < 2; ch++) {
                short8 kf = *(short8*)&Kl[(nb * 16 + l16) * KSTR + ch * 32 + quad * 8];
                c = __builtin_amdgcn_mfma_f32_16x16x32_bf16(qf[ch], kf, c, 0, 0, 0);
            }
            sB[nb] = c;
        }

        // ---- mask + online softmax (C-layout: row=quad*4+r, col=kv0+nb*16+l16) ----
        float alpha[4];
#pragma unroll
        for (int r = 0; r < 4; r++) {
            const int rg = q0 + wave * 16 + quad * 4 + r;
#pragma unroll
            for (int nb = 0; nb < 4; nb++) {
                const int kk = kv0 + nb * 16 + l16;
                const bool valid = (kk <= rg) && (rg - kk <= win);
                sB[nb][r] = valid ? sB[nb][r] * SCALE : -3.0e38f;
            }
            float mx = fmaxf(fmaxf(sB[0][r], sB[1][r]), fmaxf(sB[2][r], sB[3][r]));
#pragma unroll
            for (int o = 1; o < 16; o <<= 1) mx = fmaxf(mx, __shfl_xor(mx, o));
            const float mn = fmaxf(m_i[r], mx);
            const float al = exp2f((m_i[r] - mn) * LOG2E);
            m_i[r] = mn;
            float p[4], rs = 0.f;
#pragma unroll
            for (int nb = 0; nb < 4; nb++) {
                p[nb] = exp2f((sB[nb][r] - mn) * LOG2E);
                rs += p[nb];
            }
#pragma unroll
            for (int o = 1; o < 16; o <<= 1) rs += __shfl_xor(rs, o);
            l_i[r] = l_i[r] * al + rs;
            alpha[r] = al;
            const int prow = wave * 16 * PSTR + (quad * 4 + r) * PSTR;
#pragma unroll
            for (int nb = 0; nb < 4; nb++)
                Pl[prow + nb * 16 + l16] = f2bf(p[nb]);
        }
#pragma unroll
        for (int nb = 0; nb < 4; nb++)
#pragma unroll
            for (int r = 0; r < 4; r++) acc[nb][r] *= alpha[r];

        // ---- P (C-layout) -> A-layout via per-wave LDS round trip ----
        __asm__ volatile("" ::: "memory");   // keep write->read order; DS is in-order per wave
        short8 pf[2];
#pragma unroll
        for (int ch = 0; ch < 2; ch++)
            pf[ch] = *(short8*)&Pl[wave * 16 * PSTR + l16 * PSTR + ch * 32 + quad * 8];

        // ---- O += P V : 4 d-blocks x 2 key-chunks ----
#pragma unroll
        for (int nb = 0; nb < 4; nb++) {
#pragma unroll
            for (int ch = 0; ch < 2; ch++) {
                short8 vf = *(short8*)&Vt[(nb * 16 + l16) * VSTR + ch * 32 + quad * 8];
                acc[nb] = __builtin_amdgcn_mfma_f32_16x16x32_bf16(pf[ch], vf, acc[nb], 0, 0, 0);
            }
        }
    }

    // ---- epilogue: O / l, store (C-layout -> coalesced 64B per quad-row) ----
#pragma unroll
    for (int r = 0; r < 4; r++) {
        const float inv = 1.0f / l_i[r];
        const int rg = q0 + wave * 16 + quad * 4 + r;
        float* dst = Op + (size_t)rg * Dc;
#pragma unroll
        for (int nb = 0; nb < 4; nb++)
            dst[nb * 16 + l16] = acc[nb][r] * inv;
    }
}

extern "C" void kernel_launch(void* const* d_in, const int* in_sizes, int n_in,
                              void* d_out, int out_size, void* d_ws, size_t ws_size,
                              hipStream_t stream) {
    (void)in_sizes; (void)n_in; (void)d_ws; (void)ws_size; (void)out_size;
    const float* Q = (const float*)d_in[0];
    const float* K = (const float*)d_in[1];
    const float* V = (const float*)d_in[2];
    const int* wsz = (const int*)d_in[3];
    float* Out = (float*)d_out;

    dim3 grid(Bc * Hc * (Tc / BQ));   // 1024 blocks
    dim3 block(256);                  // 4 waves
    dswa_kernel<<<grid, block, 0, stream>>>(Q, K, V, wsz, Out);
}

// Round 2
// 177.879 us; speedup vs baseline: 1.0911x; 1.0911x over previous
//
#include <hip/hip_runtime.h>

// DynamicSlidingWindowAttention — flash attention, bf16 MFMA, gfx950.
// R2: 8-wave blocks with 2-way KV split (tail-imbalance fix) + transposed
// S^T = K·Q^T softmax (in-lane reductions, per-lane m/l scalars).
// Layouts (m89/m91/m120-verified):
//   mfma_f32_16x16x32_bf16: A[m=lane&15][k=quad*8+j], B[k=quad*8+j][n=lane&15],
//   C/D: col=lane&15, row=quad*4+reg.

constexpr int Bc = 2, Hc = 16, Tc = 2048, Dc = 64;
constexpr int BQ = 64;     // q rows per block (16 per wave-slot wv)
constexpr int BK = 64;     // keys per kv tile
constexpr int KSTR = 72;   // LDS row strides (ushort) — pad keeps conflicts <=2-way
constexpr int VSTR = 72;
constexpr int PSTR = 72;
constexpr float SCALE = 0.125f;  // 1/sqrt(64), folded into Q
constexpr float LOG2E = 1.44269504088896340736f;

// LDS map (ushort offsets), total 27648 ushorts = 55296 B -> 2 blocks/CU:
//   K buffers : g*4608            (g=0,1)   [0,     9216)
//   V buffers : 9216 + g*4608               [9216, 18432)
//   P buffers : 18432 + wave*1152 (w=0..7)  [18432,27648)
constexpr int KOFF = 0;
constexpr int VOFF = 9216;
constexpr int POFF = 18432;

typedef __attribute__((ext_vector_type(8))) short short8;
typedef __attribute__((ext_vector_type(4))) float float4v;

__device__ inline unsigned f2bf_u(float f) {
    union { float f; unsigned u; } v; v.f = f;
    return (v.u + 0x7fffu + ((v.u >> 16) & 1u)) >> 16;   // RNE, as uint
}

__device__ inline short8 pack8(const float* t) {
    short8 r;
#pragma unroll
    for (int j = 0; j < 8; j++) r[j] = (short)f2bf_u(t[j]);
    return r;
}

__global__ __launch_bounds__(512, 4)
void dswa_kernel(const float* __restrict__ Q, const float* __restrict__ K,
                 const float* __restrict__ V, const int* __restrict__ wsz,
                 float* __restrict__ O) {
    __shared__ __align__(16) unsigned short LDS[27648];

    const int blk = blockIdx.x;
    const int qt = blk & 31;
    const int h  = (blk >> 5) & 15;
    const int b  = blk >> 9;
    const int q0 = qt * BQ;
    const int win = wsz[h];

    const int tid  = threadIdx.x;
    const int g    = tid >> 8;          // kv-split group 0/1 (waves 0-3 / 4-7)
    const int ltid = tid & 255;         // tid within group
    const int wave = tid >> 6;          // 0..7
    const int wv   = wave & 3;          // q-row group within block
    const int lane = tid & 63;
    const int quad = lane >> 4;
    const int l16  = lane & 15;

    const size_t headoff = (size_t)(b * Hc + h) * Tc * Dc;
    const float* Qp = Q + headoff;
    const float* Kp = K + headoff;
    const float* Vp = V + headoff;
    float*       Op = O + headoff;

    unsigned short* Kl = &LDS[KOFF + g * 4608];
    unsigned short* Vt = &LDS[VOFF + g * 4608];
    unsigned short* Pl = &LDS[POFF + wave * 1152];

    // ---- Q fragments, pre-scaled by 1/sqrt(d). Row = q0 + wv*16 + l16 ----
    short8 qf[2];
    {
        const int qrow = q0 + wv * 16 + l16;
#pragma unroll
        for (int c = 0; c < 2; c++) {
            const float* src = Qp + (size_t)qrow * Dc + c * 32 + quad * 8;
            float4v a = *(const float4v*)src;
            float4v d4 = *(const float4v*)(src + 4);
            float t[8] = {a[0]*SCALE, a[1]*SCALE, a[2]*SCALE, a[3]*SCALE,
                          d4[0]*SCALE, d4[1]*SCALE, d4[2]*SCALE, d4[3]*SCALE};
            qf[c] = pack8(t);
        }
    }

    float m_i = -1e30f, l_i = 0.0f;      // per-lane: one q-row (l16) each
    float4v acc[4];                       // C-layout: row=quad*4+r (qrow), col=l16 (d)
#pragma unroll
    for (int nb = 0; nb < 4; nb++) acc[nb] = (float4v){0.f, 0.f, 0.f, 0.f};

    const int kv_lo = (max(0, q0 - win)) & ~(BK - 1);
    const int n_tiles = (q0 + BQ - kv_lo) >> 6;
    const int IT = (n_tiles + 1) >> 1;   // ceil(n/2), uniform across block

    const int rg_rel0 = q0 + wv * 16 + l16 - quad * 4;   // row - kv0 base helper

    for (int t = 0; t < IT; ++t) {
        const int ti = g + 2 * t;
        const bool act = ti < n_tiles;
        const int kv0 = kv_lo + ti * BK;

        __syncthreads();   // previous iteration's LDS reads complete

        if (act) {
            // stage K tile [key][d] (coalesced float4 reads, b128 LDS writes)
#pragma unroll
            for (int i = 0; i < 2; i++) {
                const int key = (ltid >> 3) + 32 * i;
                const int ds = (ltid & 7) * 8;
                const float* src = Kp + (size_t)(kv0 + key) * Dc + ds;
                float4v a = *(const float4v*)src;
                float4v d4 = *(const float4v*)(src + 4);
                float tt[8] = {a[0], a[1], a[2], a[3], d4[0], d4[1], d4[2], d4[3]};
                *(short8*)&Kl[key * KSTR + ds] = pack8(tt);
            }
            // stage V^T tile [d][key]
#pragma unroll
            for (int i = 0; i < 2; i++) {
                const int d = ltid & 63;
                const int kb = (ltid >> 6) * 8 + 32 * i;
                float tt[8];
#pragma unroll
                for (int j = 0; j < 8; j++) tt[j] = Vp[(size_t)(kv0 + kb + j) * Dc + d];
                *(short8*)&Vt[d * VSTR + kb] = pack8(tt);
            }
        }
        __syncthreads();

        if (act) {
            // ---- S^T = K Q^T: 4 m-blocks of 16 keys. Lane: qrow=l16, key=mb*16+quad*4+r
            float4v sT[4];
#pragma unroll
            for (int mb = 0; mb < 4; mb++) {
                float4v c = {0.f, 0.f, 0.f, 0.f};
#pragma unroll
                for (int ch = 0; ch < 2; ch++) {
                    short8 kf = *(short8*)&Kl[(mb * 16 + l16) * KSTR + ch * 32 + quad * 8];
                    c = __builtin_amdgcn_mfma_f32_16x16x32_bf16(kf, qf[ch], c, 0, 0, 0);
                }
                sT[mb] = c;
            }

            // ---- mask (0 <= rg-kk <= win as one unsigned cmp) ----
            const int dbase = rg_rel0 - kv0;
#pragma unroll
            for (int mb = 0; mb < 4; mb++)
#pragma unroll
                for (int r = 0; r < 4; r++) {
                    const unsigned diff = (unsigned)(dbase - mb * 16 - r);
                    sT[mb][r] = (diff <= (unsigned)win) ? sT[mb][r] : -3.0e38f;
                }

            // ---- online softmax: in-lane over 16 keys + 2 cross-quad shfl ----
            float mx = fmaxf(fmaxf(sT[0][0], sT[0][1]), fmaxf(sT[0][2], sT[0][3]));
#pragma unroll
            for (int mb = 1; mb < 4; mb++)
                mx = fmaxf(mx, fmaxf(fmaxf(sT[mb][0], sT[mb][1]),
                                     fmaxf(sT[mb][2], sT[mb][3])));
            mx = fmaxf(mx, __shfl_xor(mx, 16));
            mx = fmaxf(mx, __shfl_xor(mx, 32));

            const float mn = fmaxf(m_i, mx);
            const float al = exp2f((m_i - mn) * LOG2E);
            m_i = mn;

            float rs = 0.f;
            float p[4][4];
#pragma unroll
            for (int mb = 0; mb < 4; mb++)
#pragma unroll
                for (int r = 0; r < 4; r++) {
                    p[mb][r] = exp2f((sT[mb][r] - mn) * LOG2E);
                    rs += p[mb][r];
                }
            rs += __shfl_xor(rs, 16);
            rs += __shfl_xor(rs, 32);
            l_i = l_i * al + rs;

            // ---- P -> per-wave LDS as [qrow=l16][key], packed b64 writes ----
#pragma unroll
            for (int mb = 0; mb < 4; mb++) {
                unsigned u0 = f2bf_u(p[mb][0]) | (f2bf_u(p[mb][1]) << 16);
                unsigned u1 = f2bf_u(p[mb][2]) | (f2bf_u(p[mb][3]) << 16);
                unsigned* dst = (unsigned*)&Pl[l16 * PSTR + mb * 16 + quad * 4];
                dst[0] = u0; dst[1] = u1;
            }

            // ---- rescale acc by alpha (broadcast per acc-row) ----
            float af[4];
#pragma unroll
            for (int r = 0; r < 4; r++) af[r] = __shfl(al, quad * 4 + r);
#pragma unroll
            for (int nb = 0; nb < 4; nb++)
#pragma unroll
                for (int r = 0; r < 4; r++) acc[nb][r] *= af[r];

            // ---- O += P V ----
            __asm__ volatile("" ::: "memory");
            short8 pf[2];
#pragma unroll
            for (int ch = 0; ch < 2; ch++)
                pf[ch] = *(short8*)&Pl[l16 * PSTR + ch * 32 + quad * 8];
#pragma unroll
            for (int nb = 0; nb < 4; nb++) {
#pragma unroll
                for (int ch = 0; ch < 2; ch++) {
                    short8 vf = *(short8*)&Vt[(nb * 16 + l16) * VSTR + ch * 32 + quad * 8];
                    acc[nb] = __builtin_amdgcn_mfma_f32_16x16x32_bf16(pf[ch], vf, acc[nb], 0, 0, 0);
                }
            }
        }
    }

    // ---- merge the two KV-split partials through LDS, then store ----
    __syncthreads();
    float* fl = (float*)LDS;
    // m: fl[0..63] by (wv*16+l16); l: fl[64..127]; acc: fl[128 + row*65 + col]
    if (g == 1) {
        if (quad == 0) {
            fl[wv * 16 + l16] = m_i;
            fl[64 + wv * 16 + l16] = l_i;
        }
#pragma unroll
        for (int r = 0; r < 4; r++) {
            const int row = wv * 16 + quad * 4 + r;
#pragma unroll
            for (int nb = 0; nb < 4; nb++)
                fl[128 + row * 65 + nb * 16 + l16] = acc[nb][r];
        }
    }
    __syncthreads();
    if (g == 0) {
        const float m1 = fl[wv * 16 + l16];
        const float l1 = fl[64 + wv * 16 + l16];
        const float M  = fmaxf(m_i, m1);
        const float a0 = exp2f((m_i - M) * LOG2E);
        const float a1 = exp2f((m1 - M) * LOG2E);
        const float lt = l_i * a0 + l1 * a1;
        const float inv = 1.0f / lt;
        float c0[4], c1[4], iv[4];
#pragma unroll
        for (int r = 0; r < 4; r++) {
            c0[r] = __shfl(a0, quad * 4 + r);
            c1[r] = __shfl(a1, quad * 4 + r);
            iv[r] = __shfl(inv, quad * 4 + r);
        }
#pragma unroll
        for (int r = 0; r < 4; r++) {
            const int row = wv * 16 + quad * 4 + r;
            float* dst = Op + (size_t)(q0 + row) * Dc;
#pragma unroll
            for (int nb = 0; nb < 4; nb++) {
                const float o1 = fl[128 + row * 65 + nb * 16 + l16];
                dst[nb * 16 + l16] = (acc[nb][r] * c0[r] + o1 * c1[r]) * iv[r];
            }
        }
    }
}

extern "C" void kernel_launch(void* const* d_in, const int* in_sizes, int n_in,
                              void* d_out, int out_size, void* d_ws, size_t ws_size,
                              hipStream_t stream) {
    (void)in_sizes; (void)n_in; (void)d_ws; (void)ws_size; (void)out_size;
    const float* Q = (const float*)d_in[0];
    const float* K = (const float*)d_in[1];
    const float* V = (const float*)d_in[2];
    const int* wsz = (const int*)d_in[3];
    float* Out = (float*)d_out;

    dim3 grid(Bc * Hc * (Tc / BQ));   // 1024 blocks
    dim3 block(512);                  // 8 waves: 2 KV-split groups x 4
    dswa_kernel<<<grid, block, 0, stream>>>(Q, K, V, wsz, Out);
}

// Round 3
// 140.781 us; speedup vs baseline: 1.3786x; 1.2635x over previous
//
#include <hip/hip_runtime.h>

// DynamicSlidingWindowAttention — flash attention, bf16 MFMA, gfx950.
// R3: persistent 512 blocks + atomic work-stealing (counter in d_ws),
// heavy-first item order (descending window, descending qt). Fixes the
// scheduling tail seen in R2 (Occupancy 19%, nothing saturated).
// Body = R2: 8 waves, 2-way KV split, S^T = K·Q^T softmax, log2-domain.
// Layouts (m89/m91/m120-verified):
//   mfma_f32_16x16x32_bf16: A[m=lane&15][k=quad*8+j], B[k=quad*8+j][n=lane&15],
//   C/D: col=lane&15, row=quad*4+reg.

constexpr int Bc = 2, Hc = 16, Tc = 2048, Dc = 64;
constexpr int BQ = 64;     // q rows per item (16 per wave-slot wv)
constexpr int BK = 64;     // keys per kv tile
constexpr int KSTR = 72;   // LDS row strides (ushort); 144B rows keep b128 aligned
constexpr int VSTR = 72;
constexpr int PSTR = 72;
constexpr int N_ITEMS = Bc * Hc * (Tc / BQ);   // 1024
// scores in log2 domain: fold 1/sqrt(64) * log2(e) into Q
constexpr float QSCALE = 0.125f * 1.44269504088896340736f;

// LDS map (ushort offsets), K/V/P = 55296 B; +8B broadcast slot.
constexpr int KOFF = 0;
constexpr int VOFF = 9216;
constexpr int POFF = 18432;
constexpr int IBOFF = 27648;   // ushort idx of item-broadcast (int)

typedef __attribute__((ext_vector_type(8))) short short8;
typedef __attribute__((ext_vector_type(4))) float float4v;

__device__ inline unsigned f2bf_u(float f) {
    union { float f; unsigned u; } v; v.f = f;
    return (v.u + 0x7fffu + ((v.u >> 16) & 1u)) >> 16;   // RNE, as uint
}

__device__ inline short8 pack8(const float* t) {
    short8 r;
#pragma unroll
    for (int j = 0; j < 8; j++) r[j] = (short)f2bf_u(t[j]);
    return r;
}

__global__ __launch_bounds__(512, 2)
void dswa_kernel(const float* __restrict__ Q, const float* __restrict__ K,
                 const float* __restrict__ V, const int* __restrict__ wsz,
                 float* __restrict__ O, unsigned* __restrict__ counter) {
    __shared__ __align__(16) unsigned short LDS[27648 + 8];

    const int tid  = threadIdx.x;
    const int g    = tid >> 8;          // kv-split group 0/1
    const int ltid = tid & 255;
    const int wave = tid >> 6;          // 0..7
    const int wv   = wave & 3;          // q-row group
    const int lane = tid & 63;
    const int quad = lane >> 4;
    const int l16  = lane & 15;

    unsigned short* Kl = &LDS[KOFF + g * 4608];
    unsigned short* Vt = &LDS[VOFF + g * 4608];
    unsigned short* Pl = &LDS[POFF + wave * 1152];
    int* ib = (int*)&LDS[IBOFF];

    for (;;) {
        if (tid == 0) *ib = (int)atomicAdd(counter, 1u);
        __syncthreads();
        const int idx = *ib;
        if (idx >= N_ITEMS) break;

        // heavy-first decode: h descending (largest window first), qt descending
        const int b  = idx & 1;
        const int qt = 31 - ((idx >> 1) & 31);
        const int h  = 15 - (idx >> 6);
        const int q0 = qt * BQ;
        const int win = wsz[h];

        const size_t headoff = (size_t)(b * Hc + h) * Tc * Dc;
        const float* Qp = Q + headoff;
        const float* Kp = K + headoff;
        const float* Vp = V + headoff;
        float*       Op = O + headoff;

        // ---- Q fragments, pre-scaled by QSCALE (log2 domain) ----
        short8 qf[2];
        {
            const int qrow = q0 + wv * 16 + l16;
#pragma unroll
            for (int c = 0; c < 2; c++) {
                const float* src = Qp + (size_t)qrow * Dc + c * 32 + quad * 8;
                float4v a = *(const float4v*)src;
                float4v d4 = *(const float4v*)(src + 4);
                float t[8] = {a[0]*QSCALE, a[1]*QSCALE, a[2]*QSCALE, a[3]*QSCALE,
                              d4[0]*QSCALE, d4[1]*QSCALE, d4[2]*QSCALE, d4[3]*QSCALE};
                qf[c] = pack8(t);
            }
        }

        float m_i = -1e30f, l_i = 0.0f;   // per-lane q-row = l16 (log2 domain)
        float4v acc[4];
#pragma unroll
        for (int nb = 0; nb < 4; nb++) acc[nb] = (float4v){0.f, 0.f, 0.f, 0.f};

        const int kv_lo = (max(0, q0 - win)) & ~(BK - 1);
        const int n_tiles = (q0 + BQ - kv_lo) >> 6;
        const int IT = (n_tiles + 1) >> 1;

        const int rg_rel0 = q0 + wv * 16 + l16 - quad * 4;

        for (int t = 0; t < IT; ++t) {
            const int ti = g + 2 * t;
            const bool act = ti < n_tiles;
            const int kv0 = kv_lo + ti * BK;

            __syncthreads();   // prev iteration's LDS reads complete

            if (act) {
                // stage K tile [key][d]
#pragma unroll
                for (int i = 0; i < 2; i++) {
                    const int key = (ltid >> 3) + 32 * i;
                    const int ds = (ltid & 7) * 8;
                    const float* src = Kp + (size_t)(kv0 + key) * Dc + ds;
                    float4v a = *(const float4v*)src;
                    float4v d4 = *(const float4v*)(src + 4);
                    float tt[8] = {a[0], a[1], a[2], a[3], d4[0], d4[1], d4[2], d4[3]};
                    *(short8*)&Kl[key * KSTR + ds] = pack8(tt);
                }
                // stage V^T tile [d][key]
#pragma unroll
                for (int i = 0; i < 2; i++) {
                    const int d = ltid & 63;
                    const int kb = (ltid >> 6) * 8 + 32 * i;
                    float tt[8];
#pragma unroll
                    for (int j = 0; j < 8; j++) tt[j] = Vp[(size_t)(kv0 + kb + j) * Dc + d];
                    *(short8*)&Vt[d * VSTR + kb] = pack8(tt);
                }
            }
            __syncthreads();

            if (act) {
                // ---- S^T = K Q^T (log2 domain) ----
                float4v sT[4];
#pragma unroll
                for (int mb = 0; mb < 4; mb++) {
                    float4v c = {0.f, 0.f, 0.f, 0.f};
#pragma unroll
                    for (int ch = 0; ch < 2; ch++) {
                        short8 kf = *(short8*)&Kl[(mb * 16 + l16) * KSTR + ch * 32 + quad * 8];
                        c = __builtin_amdgcn_mfma_f32_16x16x32_bf16(kf, qf[ch], c, 0, 0, 0);
                    }
                    sT[mb] = c;
                }

                // ---- mask: 0 <= qrow - key <= win via one unsigned cmp ----
                const int dbase = rg_rel0 - kv0;
#pragma unroll
                for (int mb = 0; mb < 4; mb++)
#pragma unroll
                    for (int r = 0; r < 4; r++) {
                        const unsigned diff = (unsigned)(dbase - mb * 16 - r);
                        sT[mb][r] = (diff <= (unsigned)win) ? sT[mb][r] : -3.0e38f;
                    }

                // ---- online softmax: in-lane over 16 keys + 2 shfl ----
                float mx = fmaxf(fmaxf(sT[0][0], sT[0][1]), fmaxf(sT[0][2], sT[0][3]));
#pragma unroll
                for (int mb = 1; mb < 4; mb++)
                    mx = fmaxf(mx, fmaxf(fmaxf(sT[mb][0], sT[mb][1]),
                                         fmaxf(sT[mb][2], sT[mb][3])));
                mx = fmaxf(mx, __shfl_xor(mx, 16));
                mx = fmaxf(mx, __shfl_xor(mx, 32));

                const float mn = fmaxf(m_i, mx);
                const float al = exp2f(m_i - mn);
                m_i = mn;

                float rs = 0.f;
                float p[4][4];
#pragma unroll
                for (int mb = 0; mb < 4; mb++)
#pragma unroll
                    for (int r = 0; r < 4; r++) {
                        p[mb][r] = exp2f(sT[mb][r] - mn);
                        rs += p[mb][r];
                    }
                rs += __shfl_xor(rs, 16);
                rs += __shfl_xor(rs, 32);
                l_i = l_i * al + rs;

                // ---- P -> per-wave LDS [qrow=l16][key], packed dword writes ----
#pragma unroll
                for (int mb = 0; mb < 4; mb++) {
                    unsigned u0 = f2bf_u(p[mb][0]) | (f2bf_u(p[mb][1]) << 16);
                    unsigned u1 = f2bf_u(p[mb][2]) | (f2bf_u(p[mb][3]) << 16);
                    unsigned* dst = (unsigned*)&Pl[l16 * PSTR + mb * 16 + quad * 4];
                    dst[0] = u0; dst[1] = u1;
                }

                // ---- rescale acc by alpha ----
                float af[4];
#pragma unroll
                for (int r = 0; r < 4; r++) af[r] = __shfl(al, quad * 4 + r);
#pragma unroll
                for (int nb = 0; nb < 4; nb++)
#pragma unroll
                    for (int r = 0; r < 4; r++) acc[nb][r] *= af[r];

                // ---- O += P V ----
                __asm__ volatile("" ::: "memory");
                short8 pf[2];
#pragma unroll
                for (int ch = 0; ch < 2; ch++)
                    pf[ch] = *(short8*)&Pl[l16 * PSTR + ch * 32 + quad * 8];
#pragma unroll
                for (int nb = 0; nb < 4; nb++) {
#pragma unroll
                    for (int ch = 0; ch < 2; ch++) {
                        short8 vf = *(short8*)&Vt[(nb * 16 + l16) * VSTR + ch * 32 + quad * 8];
                        acc[nb] = __builtin_amdgcn_mfma_f32_16x16x32_bf16(pf[ch], vf, acc[nb], 0, 0, 0);
                    }
                }
            }
        }

        // ---- merge the two KV-split partials through LDS, then store ----
        __syncthreads();
        float* fl = (float*)LDS;
        if (g == 1) {
            if (quad == 0) {
                fl[wv * 16 + l16] = m_i;
                fl[64 + wv * 16 + l16] = l_i;
            }
#pragma unroll
            for (int r = 0; r < 4; r++) {
                const int row = wv * 16 + quad * 4 + r;
#pragma unroll
                for (int nb = 0; nb < 4; nb++)
                    fl[128 + row * 65 + nb * 16 + l16] = acc[nb][r];
            }
        }
        __syncthreads();
        if (g == 0) {
            const float m1 = fl[wv * 16 + l16];
            const float l1 = fl[64 + wv * 16 + l16];
            const float M  = fmaxf(m_i, m1);
            const float a0 = exp2f(m_i - M);
            const float a1 = exp2f(m1 - M);
            const float lt = l_i * a0 + l1 * a1;
            const float inv = 1.0f / lt;
            float c0[4], c1[4], iv[4];
#pragma unroll
            for (int r = 0; r < 4; r++) {
                c0[r] = __shfl(a0, quad * 4 + r);
                c1[r] = __shfl(a1, quad * 4 + r);
                iv[r] = __shfl(inv, quad * 4 + r);
            }
#pragma unroll
            for (int r = 0; r < 4; r++) {
                const int row = wv * 16 + quad * 4 + r;
                float* dst = Op + (size_t)(q0 + row) * Dc;
#pragma unroll
                for (int nb = 0; nb < 4; nb++) {
                    const float o1 = fl[128 + row * 65 + nb * 16 + l16];
                    dst[nb * 16 + l16] = (acc[nb][r] * c0[r] + o1 * c1[r]) * iv[r];
                }
            }
        }
        // next loop iteration's broadcast barrier protects fl reads
    }
}

extern "C" void kernel_launch(void* const* d_in, const int* in_sizes, int n_in,
                              void* d_out, int out_size, void* d_ws, size_t ws_size,
                              hipStream_t stream) {
    (void)in_sizes; (void)n_in; (void)ws_size; (void)out_size;
    const float* Q = (const float*)d_in[0];
    const float* K = (const float*)d_in[1];
    const float* V = (const float*)d_in[2];
    const int* wsz = (const int*)d_in[3];
    float* Out = (float*)d_out;
    unsigned* counter = (unsigned*)d_ws;

    hipMemsetAsync(counter, 0, sizeof(unsigned), stream);
    dim3 grid(512);    // exactly resident capacity: 2 blocks/CU x 256 CU
    dim3 block(512);   // 8 waves: 2 KV-split groups x 4
    dswa_kernel<<<grid, block, 0, stream>>>(Q, K, V, wsz, Out, counter);
}